// Round 1
// baseline (889.318 us; speedup 1.0000x reference)
//
#include <hip/hip_runtime.h>

typedef __attribute__((ext_vector_type(8))) short short8;
typedef __attribute__((ext_vector_type(4))) float f32x4;

#define C2 (-0.7213475204444817f)   /* -0.5 * log2(e) : K = exp2(C2*dist2) */
#define LOG2E 1.4426950408889634f

static __device__ __forceinline__ unsigned short f2bf(float f) {
    unsigned u = __float_as_uint(f);
    u = u + 0x7FFFu + ((u >> 16) & 1u);      // round-to-nearest-even
    return (unsigned short)(u >> 16);
}

// Kernel A: per-tile KDE density (MFMA gram) + MLP + sigmoid -> coarse attn
// attn layout: (B, hh, ww, C) = (8, 32, 32, 128) f32, contiguous
__global__ __launch_bounds__(256)
void kdeA(const float* __restrict__ x,  const float* __restrict__ w1,
          const float* __restrict__ b1, const float* __restrict__ w2,
          const float* __restrict__ b2, float* __restrict__ attn)
{
    __shared__ unsigned short g_lds[8192];   // 4 grp * 32c * 64w bf16, XOR-swizzled
    __shared__ float sq_lds[128];
    __shared__ float dens_lds[128];
    __shared__ float y1_lds[32];

    // XCD-chunked swizzle: 8192 blocks, XCD k processes tiles [k*1024,(k+1)*1024)
    int bid  = blockIdx.x;
    int tile = ((bid & 7) << 10) | (bid >> 3);
    int b  = tile >> 10;
    int ti = (tile >> 5) & 31;
    int tj = tile & 31;
    int t  = threadIdx.x;

    // ---- stage x tile -> bf16 LDS, per group layout [c][w], w = wy*8+wx ----
    const float* xb = x + (size_t)b * 8388608 + ti * 2048 + tj * 8;
    #pragma unroll
    for (int k = 0; k < 4; ++k) {
        int p   = t + (k << 8);          // 0..1023 = ch*8 + row
        int ch  = p >> 3;
        int row = p & 7;
        const float* src = xb + ch * 65536 + row * 256;
        f32x4 lo = *(const f32x4*)src;
        f32x4 hi = *(const f32x4*)(src + 4);
        short8 v;
        v[0] = (short)f2bf(lo[0]); v[1] = (short)f2bf(lo[1]);
        v[2] = (short)f2bf(lo[2]); v[3] = (short)f2bf(lo[3]);
        v[4] = (short)f2bf(hi[0]); v[5] = (short)f2bf(hi[1]);
        v[6] = (short)f2bf(hi[2]); v[7] = (short)f2bf(hi[3]);
        int grp = ch >> 5, cl = ch & 31;
        int off = (grp << 12) + ((((cl << 7) + (row << 4))) ^ ((cl & 7) << 4));
        *(short8*)((char*)g_lds + off) = v;
    }
    __syncthreads();

    // ---- per-wave 32x32 gram via 16x16x32 bf16 MFMA (A==B fragment) ----
    int wave = t >> 6, lane = t & 63;
    int l15 = lane & 15, h = lane >> 4;
    const char* gb = (const char*)g_lds + (wave << 12);

    short8 frag[2][2];
    #pragma unroll
    for (int tt = 0; tt < 2; ++tt)
        #pragma unroll
        for (int ks = 0; ks < 2; ++ks) {
            int c = (tt << 4) | l15;
            int off = (((c << 7) + (ks << 6) + (h << 4))) ^ ((c & 7) << 4);
            frag[tt][ks] = *(const short8*)(gb + off);
        }

    f32x4 acc[2][2] = {};
    #pragma unroll
    for (int ks = 0; ks < 2; ++ks)
        #pragma unroll
        for (int mi = 0; mi < 2; ++mi)
            #pragma unroll
            for (int ni = 0; ni < 2; ++ni)
                acc[mi][ni] = __builtin_amdgcn_mfma_f32_16x16x32_bf16(
                    frag[mi][ks], frag[ni][ks], acc[mi][ni], 0, 0, 0);

    // diag (= sq) extraction: row-in-tile 4h+reg == col l15
    if (h == (l15 >> 2)) {
        sq_lds[(wave << 5) + l15]      = acc[0][0][l15 & 3];
        sq_lds[(wave << 5) + 16 + l15] = acc[1][1][l15 & 3];
    }
    __syncthreads();

    float sqc0 = sq_lds[(wave << 5) + l15];
    float sqc1 = sq_lds[(wave << 5) + 16 + l15];
    f32x4 sqr0 = *(const f32x4*)&sq_lds[(wave << 5) + (h << 2)];
    f32x4 sqr1 = *(const f32x4*)&sq_lds[(wave << 5) + 16 + (h << 2)];

    float P0 = 0.f, P1 = 0.f;
    #pragma unroll
    for (int r = 0; r < 4; ++r) {
        P0 += exp2f(C2 * fmaxf(sqr0[r] + sqc0 - 2.f * acc[0][0][r], 0.f));
        P0 += exp2f(C2 * fmaxf(sqr1[r] + sqc0 - 2.f * acc[1][0][r], 0.f));
        P1 += exp2f(C2 * fmaxf(sqr0[r] + sqc1 - 2.f * acc[0][1][r], 0.f));
        P1 += exp2f(C2 * fmaxf(sqr1[r] + sqc1 - 2.f * acc[1][1][r], 0.f));
    }
    // sum over the 4 lanes sharing l15 (K is symmetric: col-sum == row-sum)
    P0 += __shfl_xor(P0, 16); P0 += __shfl_xor(P0, 32);
    P1 += __shfl_xor(P1, 16); P1 += __shfl_xor(P1, 32);
    if (h == 0) {
        dens_lds[(wave << 5) + l15]      = P0 * 0.03125f;
        dens_lds[(wave << 5) + 16 + l15] = P1 * 0.03125f;
    }
    __syncthreads();

    // ---- MLP: y1 = relu(w1 @ dens + b1) ----
    if (t < 32) {
        const f32x4* wr = (const f32x4*)(w1 + (t << 7));
        const f32x4* dv = (const f32x4*)dens_lds;
        float a0 = 0.f, a1 = 0.f, a2 = 0.f, a3 = 0.f;
        #pragma unroll
        for (int q = 0; q < 32; ++q) {
            f32x4 wv = wr[q]; f32x4 dd = dv[q];
            a0 += wv[0] * dd[0]; a1 += wv[1] * dd[1];
            a2 += wv[2] * dd[2]; a3 += wv[3] * dd[3];
        }
        y1_lds[t] = fmaxf(a0 + a1 + a2 + a3 + b1[t], 0.f);
    }
    __syncthreads();
    // ---- y2 = w2 @ y1 + b2 ; attn = sigmoid(y2) + 0.5 ----
    if (t < 128) {
        const f32x4* wr = (const f32x4*)(w2 + (t << 5));
        const f32x4* yv = (const f32x4*)y1_lds;
        float a0 = 0.f, a1 = 0.f, a2 = 0.f, a3 = 0.f;
        #pragma unroll
        for (int q = 0; q < 8; ++q) {
            f32x4 wv = wr[q]; f32x4 yy = yv[q];
            a0 += wv[0] * yy[0]; a1 += wv[1] * yy[1];
            a2 += wv[2] * yy[2]; a3 += wv[3] * yy[3];
        }
        float y2 = a0 + a1 + a2 + a3 + b2[t];
        float s  = 1.0f / (1.0f + exp2f(-LOG2E * y2));
        attn[(((size_t)b << 10) + (ti << 5) + tj) * 128 + t] = s + 0.5f;
    }
}

// Kernel B: align-corners bilinear x8 upsample of attn, multiply with x
__global__ __launch_bounds__(256)
void kdeB(const float* __restrict__ x, const float* __restrict__ attn,
          float* __restrict__ out)
{
    const float SC = 31.0f / 255.0f;
    int tid = blockIdx.x * 256 + threadIdx.x;

    // x-direction weights are loop-invariant (stride multiple of 64 vec4/row)
    int  px = (tid & 63) << 2;
    int   x0[4]; float wx[4];
    #pragma unroll
    for (int p = 0; p < 4; ++p) {
        float xi = (float)(px + p) * SC;
        int   xq = (int)floorf(xi);
        if (xq > 30) xq = 30;
        x0[p] = xq * 128;
        wx[p] = xi - (float)xq;
    }

    const f32x4* xv = (const f32x4*)x;
    f32x4* ov = (f32x4*)out;
    const int stride = gridDim.x * 256;

    for (int idx = tid; idx < 16777216; idx += stride) {
        int y  = (idx >> 6) & 255;
        int bc = idx >> 14;          // b*128 + c
        int c  = bc & 127;
        int b  = bc >> 7;

        float yi = (float)y * SC;
        int   y0 = (int)floorf(yi);
        if (y0 > 30) y0 = 30;
        float wy  = yi - (float)y0;
        float wy1 = 1.0f - wy;

        const float* a0 = attn + ((size_t)b << 17) + ((y0 << 5) << 7) + c;
        const float* a1 = a0 + 4096;   // next coarse row (32*128)

        f32x4 xd = xv[idx];
        f32x4 r;
        #pragma unroll
        for (int p = 0; p < 4; ++p) {
            int o0 = x0[p];
            float v00 = a0[o0], v01 = a0[o0 + 128];
            float v10 = a1[o0], v11 = a1[o0 + 128];
            float r0 = v00 * wy1 + v10 * wy;
            float r1 = v01 * wy1 + v11 * wy;
            float a  = r0 * (1.0f - wx[p]) + r1 * wx[p];
            r[p] = xd[p] * a;
        }
        ov[idx] = r;
    }
}

extern "C" void kernel_launch(void* const* d_in, const int* in_sizes, int n_in,
                              void* d_out, int out_size, void* d_ws, size_t ws_size,
                              hipStream_t stream) {
    const float* x  = (const float*)d_in[0];
    const float* w1 = (const float*)d_in[1];
    const float* b1 = (const float*)d_in[2];
    const float* w2 = (const float*)d_in[3];
    const float* b2 = (const float*)d_in[4];
    float* out  = (float*)d_out;
    float* attn = (float*)d_ws;      // 8*32*32*128 f32 = 4 MB

    kdeA<<<8192, 256, 0, stream>>>(x, w1, b1, w2, b2, attn);
    kdeB<<<8192, 256, 0, stream>>>(x, attn, out);
}